// Round 7
// baseline (19545.334 us; speedup 1.0000x reference)
//
#include <hip/hip_runtime.h>

// GRU-D fused scan, v9: v6 + EXPLICIT AGPR residency for overflow weights.
// R11 diagnosis: every round so far lost to the same mechanism — weights
// that exceed the arch file get (a) remat'd from global (v3/v4), (b)
// scratch-spilled (v2), or (c) parked in AGPRs with a compiler-inserted
// AGPR->VGPR copy per use, even for MFMA A-operands (v7/v8: ~1100 extra
// VALU/step = 336 frag dwords round-tripped; MfmaUtil 16% active-CU).
// Fix: keep the twice-verified v3/v6 dot2 structure, but place 75 of the
// 105 h2 weights in AGPRs EXPLICITLY (v_accvgpr_write at init, one volatile
// v_accvgpr_read per use in-loop, 2cyc ea, pipelined, un-hoistable) and pin
// the remaining 30 in arch VGPRs. Arch demand ~71 <= 84 -> no remat, no
// scratch. Per-step/wave ~= 105 dot2 + 75 agpr_read + 60 misc ~= 480 cyc;
// x3 waves/SIMD + barriers ~= 1850 cyc/step (~790us) predicted.

#define BB 256
#define SS 1024
#define DD 32
#define HH 128
#define NT 768

typedef _Float16 f16;
typedef __attribute__((ext_vector_type(2))) _Float16 h2;

__device__ inline h2 as_h2(int x) { union { int i; h2 h; } u; u.i = x; return u.h; }

__device__ inline float dot2(h2 a, h2 b, float c) {
    return __builtin_amdgcn_fdot2(a, b, c, false);
}

// Pin an arch-resident packed weight (blocks rematerialization).
__device__ inline void pin(h2& v) { asm volatile("" : "+v"(v)); }

// Explicit AGPR placement: write once at init, read (2cyc) per use.
__device__ inline void ag_write(int& ag, h2 v) {
    union { h2 h; int i; } u; u.h = v;
    asm volatile("v_accvgpr_write_b32 %0, %1" : "=a"(ag) : "v"(u.i));
}
__device__ inline h2 ag_read(const int& ag) {
    int r;
    asm volatile("v_accvgpr_read_b32 %0, %1" : "=v"(r) : "a"(ag));
    return as_h2(r);
}

__device__ inline float frcp(float x) { return __builtin_amdgcn_rcpf(x); }
__device__ inline float fast_sigm(float x) { return frcp(1.0f + __expf(-x)); }
__device__ inline float fast_tanh(float x) {
    x = fminf(15.0f, fmaxf(-15.0f, x));
    float e = __expf(-2.0f * x);
    return (1.0f - e) * frcp(1.0f + e);
}

struct ImpState { float xprev, tprev; bool hasprev; };

// Wave 0 only (all 64 lanes active in the ballot). Lane l<32 owns feature l.
__device__ inline void impute_store(int i, float xv, int l, ImpState& st,
                                    f16* hxs, const float* tb) {
    bool nanp = (l < 32) && (xv != xv);
    unsigned long long bal = __ballot(nanp);
    bool mask = bal != 0ull;
    if (l < 32) {
        float imp = mask ? st.xprev : xv;
        hxs[l] = (f16)imp;
        if (!mask) st.xprev = xv;
    }
    float tcur = tb[i];
    float tdel = (i == 0) ? 0.0f : (tcur - tb[i - 1]);
    float texp = st.hasprev ? (tcur - st.tprev) : tdel;
    if (l == 32) hxs[32] = (f16)(mask ? 1.0f : 0.0f);
    if (l == 33) hxs[33] = (f16)texp;
    if (!mask) { st.hasprev = true; st.tprev = tcur; }
}

__global__
__attribute__((amdgpu_flat_work_group_size(NT, NT), amdgpu_waves_per_eu(3, 3)))
void gru_fused(
    const float* __restrict__ t_in, const float* __restrict__ x_in,
    const float* __restrict__ Wih0, const float* __restrict__ Whh0,
    const float* __restrict__ bih0, const float* __restrict__ bhh0,
    const float* __restrict__ Wih1, const float* __restrict__ Whh1,
    const float* __restrict__ bih1, const float* __restrict__ bhh1,
    float* __restrict__ out, char* __restrict__ ws)
{
    __shared__ float tb[SS];                  // timestamps (4 KB)
    __shared__ float2 pA[NT];                 // L0 partials (a,c) (6 KB)
    __shared__ float2 pB[NT];                 // L1 partials (d,e) (6 KB)
    __shared__ __align__(16) f16 h0s[HH];     // h0 state (256 B)
    __shared__ __align__(16) f16 h1s[HH];     // h1 state (256 B)
    __shared__ __align__(16) f16 hxs[48];     // imputed input, 34 used (96 B)

    const int tid = threadIdx.x;
    const int b = blockIdx.x;
    const int group = tid >= 384;       // K-half, wave-uniform (waves 0-5 / 6-11)
    const int row = tid - 384 * group;  // gate row 0..383

    // ---- pack half-rows: 75 h2 -> AGPRs, 30 h2 -> pinned arch VGPRs ----
    int agc[32], agd[32], age[11];      // whh0, wih1, whh1[0..10] in AGPR
    h2 wih0[9], whh1v[21];              // wih0, whh1[11..31] in arch
    {
        const float* p = Wih0 + row * 34;
        const int lim = 8 + group;      // group0: 8 real pairs (+1 zero pad), group1: 9
        #pragma unroll
        for (int k = 0; k < 9; k++) {
            int e = 16 * group + 2 * k;
            f16 lo = (k < lim) ? (f16)p[e]     : (f16)0.0f;
            f16 hi = (k < lim) ? (f16)p[e + 1] : (f16)0.0f;
            h2 v = {lo, hi}; wih0[k] = v;
        }
        p = Whh0 + row * HH + 64 * group;
        #pragma unroll
        for (int k = 0; k < 32; k++) {
            h2 v = {(f16)p[2*k], (f16)p[2*k+1]}; ag_write(agc[k], v);
        }
        p = Wih1 + row * HH + 64 * group;
        #pragma unroll
        for (int k = 0; k < 32; k++) {
            h2 v = {(f16)p[2*k], (f16)p[2*k+1]}; ag_write(agd[k], v);
        }
        p = Whh1 + row * HH + 64 * group;
        #pragma unroll
        for (int k = 0; k < 32; k++) {
            h2 v = {(f16)p[2*k], (f16)p[2*k+1]};
            if (k < 11) ag_write(age[k], v);
            else        whh1v[k - 11] = v;
        }
        #pragma unroll
        for (int k = 0; k < 9; k++)  pin(wih0[k]);
        #pragma unroll
        for (int k = 0; k < 21; k++) pin(whh1v[k]);
    }

    // ---- updater setup: waves 8,9 -> h0 units; waves 10,11 -> h1 units ----
    const bool isU = (tid >= 512);
    const bool isU0 = (tid >= 512 && tid < 640);
    const int j = isU0 ? (tid - 512) : (tid - 640);   // hidden unit (updaters only)
    float ubi[3], ubh[3]; float hr = 0.0f;
    if (isU) {
        const float* bi = isU0 ? bih0 : bih1;
        const float* bh = isU0 ? bhh0 : bhh1;
        #pragma unroll
        for (int q = 0; q < 3; q++) { ubi[q] = bi[j + 128*q]; ubh[q] = bh[j + 128*q]; }
    }

    // ---- prologue: tb, zero state, impute(0) ----
    for (int i2 = tid; i2 < SS; i2 += NT) tb[i2] = t_in[i2];
    if (tid < 64)        ((int*)h0s)[tid]       = 0;
    else if (tid < 128)  ((int*)h1s)[tid - 64]  = 0;
    else if (tid < 152)  ((int*)hxs)[tid - 128] = 0;

    const float* xrow = x_in + (size_t)b * SS * DD + tid;   // deref only tid<32
    ImpState st; st.xprev = 0.0f; st.tprev = 0.0f; st.hasprev = false;

    __syncthreads();
    if (tid < 64) {
        float xv0 = (tid < 32) ? xrow[0] : 0.0f;
        impute_store(0, xv0, tid, st, hxs, tb);
    }
    __syncthreads();

    // wave-uniform LDS bases for this wave's K-half
    const int4* h0v  = (const int4*)(h0s + 64 * group);   // 8x int4 = 64 f16
    const int4* h1v  = (const int4*)(h1s + 64 * group);
    const int4* hxv4 = (const int4*)(hxs + 16 * group);   // 2x int4 = 16 f16
    const int*  hxep = (const int*)(hxs + 32);            // elements 32,33

    for (int i = 0; i <= SS; ++i) {
        const bool doL0 = (i < SS), doL1 = (i > 0), doImp = (i + 1 < SS);

        // prefetch next x row for imputation (overlaps with dot phase)
        float xv_n = 0.0f;
        if (tid < 32 && doImp) xv_n = xrow[(size_t)(i + 1) * DD];

        // ---- dots: h operands via uniform ds_read_b128 broadcast ----
        float aP = 0.0f;
        {
            int4 u0 = hxv4[0], u1 = hxv4[1];
            int he = *hxep;   // group0 pairs with zero weight wih0[8]
            aP = dot2(as_h2(u0.x), wih0[0], aP);
            aP = dot2(as_h2(u0.y), wih0[1], aP);
            aP = dot2(as_h2(u0.z), wih0[2], aP);
            aP = dot2(as_h2(u0.w), wih0[3], aP);
            aP = dot2(as_h2(u1.x), wih0[4], aP);
            aP = dot2(as_h2(u1.y), wih0[5], aP);
            aP = dot2(as_h2(u1.z), wih0[6], aP);
            aP = dot2(as_h2(u1.w), wih0[7], aP);
            aP = dot2(as_h2(he),   wih0[8], aP);
        }
        float cC[4] = {0,0,0,0}, dC[4] = {0,0,0,0}, eC[4] = {0,0,0,0};
        #pragma unroll
        for (int c = 0; c < 8; ++c) {
            int4 v = h0v[c];
            cC[0] = dot2(as_h2(v.x), ag_read(agc[4*c+0]), cC[0]);
            dC[0] = dot2(as_h2(v.x), ag_read(agd[4*c+0]), dC[0]);
            cC[1] = dot2(as_h2(v.y), ag_read(agc[4*c+1]), cC[1]);
            dC[1] = dot2(as_h2(v.y), ag_read(agd[4*c+1]), dC[1]);
            cC[2] = dot2(as_h2(v.z), ag_read(agc[4*c+2]), cC[2]);
            dC[2] = dot2(as_h2(v.z), ag_read(agd[4*c+2]), dC[2]);
            cC[3] = dot2(as_h2(v.w), ag_read(agc[4*c+3]), cC[3]);
            dC[3] = dot2(as_h2(v.w), ag_read(agd[4*c+3]), dC[3]);
        }
        #pragma unroll
        for (int c = 0; c < 8; ++c) {
            int4 v = h1v[c];
            #pragma unroll
            for (int q = 0; q < 4; q++) {
                int k = 4 * c + q;
                int vv = (q == 0) ? v.x : (q == 1) ? v.y : (q == 2) ? v.z : v.w;
                h2 wk = (k < 11) ? ag_read(age[k]) : whh1v[k - 11];
                eC[q] = dot2(as_h2(vv), wk, eC[q]);
            }
        }
        float cP = (cC[0] + cC[1]) + (cC[2] + cC[3]);
        float dP = (dC[0] + dC[1]) + (dC[2] + dC[3]);
        float eP = (eC[0] + eC[1]) + (eC[2] + eC[3]);
        pA[tid] = make_float2(aP, cP);
        pB[tid] = make_float2(dP, eP);
        __syncthreads();   // B1 (lgkm only)

        // ---- update phase ----
        if (isU) {
            bool act = isU0 ? doL0 : doL1;
            if (act) {
                const float2* P = isU0 ? pA : pB;
                float2 q0a = P[j],       q0b = P[384 + j];
                float2 q1a = P[j + 128], q1b = P[384 + j + 128];
                float2 q2a = P[j + 256], q2b = P[384 + j + 256];
                float rx = q0a.x + q0b.x, rh = q0a.y + q0b.y;
                float zx = q1a.x + q1b.x, zh = q1a.y + q1b.y;
                float nx = q2a.x + q2b.x, nh = q2a.y + q2b.y;
                float r = fast_sigm(ubi[0] + ubh[0] + rx + rh);
                float z = fast_sigm(ubi[1] + ubh[1] + zx + zh);
                float n = fast_tanh(ubi[2] + nx + r * (ubh[2] + nh));
                hr = (1.0f - z) * n + z * hr;
                f16* hp = isU0 ? h0s : h1s;
                hp[j] = (f16)hr;          // LDS write, drained at B2
            }
        } else if (tid < 64 && doImp) {
            impute_store(i + 1, xv_n, tid, st, hxs, tb);
        }
        __syncthreads();   // B2 (lgkm only) -> h/hx visible for next iter
    }

    if (tid >= 640) out[(size_t)b * HH + (tid - 640)] = hr;
}

extern "C" void kernel_launch(void* const* d_in, const int* in_sizes, int n_in,
                              void* d_out, int out_size, void* d_ws, size_t ws_size,
                              hipStream_t stream) {
    gru_fused<<<dim3(BB), dim3(NT), 0, stream>>>(
        (const float*)d_in[0], (const float*)d_in[1],
        (const float*)d_in[2], (const float*)d_in[3],
        (const float*)d_in[4], (const float*)d_in[5],
        (const float*)d_in[6], (const float*)d_in[7],
        (const float*)d_in[8], (const float*)d_in[9],
        (float*)d_out, (char*)d_ws);
}

// Round 9
// 2625.262 us; speedup vs baseline: 7.4451x; 7.4451x over previous
//
#include <hip/hip_runtime.h>

// GRU-D fused scan, v11: v10 + inline-asm MFMA hazard fixes.
// R13 diagnosis of v10's NaN: "=v" MFMA dest without EARLY-CLOBBER let the
// RA overlap D with A/B/C of the same asm; v_mfma reads sources over ~16
// passes while writing D -> sources corrupted mid-flight -> inf/NaN f16.
// Also the GCN hazard recognizer cannot see inside inline asm: (a) VALU
// write -> MFMA read needs 2 waits; (b) MFMA write D -> VALU read needs
// ~18 waits (update phase reads accs right after the last MFMA).
// Fixes (no structural change): "=&v" early-clobber on D; "s_nop 1" inside
// each MFMA asm; a 3x s_nop 7 guard asm threading all accs "+v" between
// MFMAs and the update phase. Geometry/layout/impute = v8 (verified).
// Split: 56 frags (ah0,ax1,ah1-r = 224dw) acc via "a"; 28 frags (axf,
// ah1-z/n = 112dw) arch via "v". (1,1): acc 224<=256, arch ~250<=256.

#define NBLK 16
#define BS 16
#define SS 1024
#define DD 32
#define HH 128
#define NT 256
#define XSTR 72      // x row stride in f16 (64 data+pad; k=34 is bias-1 col)
#define HSTR 136     // h row stride in f16

typedef _Float16 f16;
typedef __attribute__((ext_vector_type(8))) _Float16 h8;
typedef __attribute__((ext_vector_type(2))) _Float16 h2;
typedef __attribute__((ext_vector_type(4))) float f4;
typedef __attribute__((ext_vector_type(4))) int i4;

union H8I4 { h8 h; i4 i; };

// MFMA with A in AGPRs (read in place). s_nop 1 covers any preceding VALU
// write -> MFMA read hazard; "=&v" early-clobber keeps D off A/B/C.
__device__ inline f4 mfma_a(i4 a, i4 b, f4 c) {
    f4 d;
    asm("s_nop 1\n\tv_mfma_f32_16x16x32_f16 %0, %1, %2, %3"
        : "=&v"(d) : "a"(a), "v"(b), "v"(c));
    return d;
}
// MFMA with A in arch VGPRs.
__device__ inline f4 mfma_v(i4 a, i4 b, f4 c) {
    f4 d;
    asm("s_nop 1\n\tv_mfma_f32_16x16x32_f16 %0, %1, %2, %3"
        : "=&v"(d) : "v"(a), "v"(b), "v"(c));
    return d;
}
// MFMA-write -> VALU-read drain: >=18 wait states, accs threaded through.
#define ACC_GUARD(a0,a1,a2,a3,a4,a5,a6,a7) \
    asm volatile("s_nop 7\n\ts_nop 7\n\ts_nop 7" \
        : "+v"(a0), "+v"(a1), "+v"(a2), "+v"(a3), \
          "+v"(a4), "+v"(a5), "+v"(a6), "+v"(a7))

__device__ inline float frcp(float x) { return __builtin_amdgcn_rcpf(x); }
__device__ inline float fast_sigm(float x) { return frcp(1.0f + __expf(-x)); }
__device__ inline float fast_tanh(float x) {
    x = fminf(15.0f, fmaxf(-15.0f, x));
    float e = __expf(-2.0f * x);
    return (1.0f - e) * frcp(1.0f + e);
}

__global__
__attribute__((amdgpu_flat_work_group_size(NT, NT), amdgpu_waves_per_eu(1, 1)))
void gru_fused(
    const float* __restrict__ t_in, const float* __restrict__ x_in,
    const float* __restrict__ Wih0, const float* __restrict__ Whh0,
    const float* __restrict__ bih0, const float* __restrict__ bhh0,
    const float* __restrict__ Wih1, const float* __restrict__ Whh1,
    const float* __restrict__ bih1, const float* __restrict__ bhh1,
    float* __restrict__ out, char* __restrict__ ws)
{
    __shared__ float tb[SS];                          // 4 KB
    __shared__ __align__(16) f16 xb[2][BS][XSTR];     // 4.5 KB
    __shared__ __align__(16) f16 h0b[2][BS][HSTR];    // 8.5 KB
    __shared__ __align__(16) f16 h1b[2][BS][HSTR];    // 8.5 KB

    const int tid = threadIdx.x;
    const int w   = tid >> 6;          // wave 0..3: units [32w, 32w+32)
    const int l   = tid & 63;
    const int cb  = l & 15;            // MFMA col = batch
    const int g   = l >> 4;            // k-group / C row-group
    const int blk = blockIdx.x;

    // ---- A-frags: [tile][gate q][ks]; lane row = q*128 + 32w+16t+(l&15) ----
    i4 axf[2][3][2], ah0f[2][3][4], ax1f[2][3][4], ah1f[2][3][4];
    #pragma unroll
    for (int t = 0; t < 2; t++) {
        const int arow = 32 * w + 16 * t + (l & 15);
        #pragma unroll
        for (int q = 0; q < 3; q++) {
            const int row = q * 128 + arow;
            #pragma unroll
            for (int ks = 0; ks < 2; ks++) {
                H8I4 u;
                #pragma unroll
                for (int e = 0; e < 8; e++) {
                    int k = 32 * ks + 8 * g + e;
                    float v;
                    if (k < 34)       v = Wih0[row * 34 + k];
                    else if (k == 34) v = (q < 2) ? (bih0[row] + bhh0[row])
                                                  : bih0[row];   // n: input bias
                    else              v = 0.0f;
                    u.h[e] = (f16)v;
                }
                axf[t][q][ks] = u.i;
            }
            #pragma unroll
            for (int ks = 0; ks < 4; ks++) {
                H8I4 u0, u1, u2;
                #pragma unroll
                for (int e = 0; e < 8; e++) {
                    int k = 32 * ks + 8 * g + e;
                    u0.h[e] = (f16)Whh0[row * 128 + k];
                    u1.h[e] = (f16)Wih1[row * 128 + k];
                    u2.h[e] = (f16)Whh1[row * 128 + k];
                }
                ah0f[t][q][ks] = u0.i; ax1f[t][q][ks] = u1.i; ah1f[t][q][ks] = u2.i;
            }
        }
    }

    // ---- packed biases (f16): L0 n-hidden; L1 r/z combined, n in/hidden ----
    h2 bnh0[2][2], brz1[2][4], bn1[2][4];
    #pragma unroll
    for (int t = 0; t < 2; t++)
        #pragma unroll
        for (int e = 0; e < 4; e++) {
            const int j = 32 * w + 16 * t + 4 * g + e;
            if ((e & 1) == 0)
                bnh0[t][e >> 1] = h2{(f16)bhh0[j + 256], (f16)bhh0[j + 1 + 256]};
            brz1[t][e] = h2{(f16)(bih1[j] + bhh1[j]),
                            (f16)(bih1[j + 128] + bhh1[j + 128])};
            bn1[t][e]  = h2{(f16)bih1[j + 256], (f16)bhh1[j + 256]};
        }

    // ---- persistent h state (lane-local, C layout: row 4g+e, col cb) ----
    float hr0[2][4] = {{0.f,0.f,0.f,0.f},{0.f,0.f,0.f,0.f}};
    float hr1[2][4] = {{0.f,0.f,0.f,0.f},{0.f,0.f,0.f,0.f}};

    // ---- imputation: lane handles batch ib, features fx and fx+16 ----
    const int ib = 4 * w + g;          // 4 waves x 4 groups = 16 batches
    const int fx = l & 15;
    const float* xptr = x_in + ((size_t)(blk * BS + ib) * SS) * DD;
    float xp0 = 0.0f, xp1 = 0.0f, tprev = 0.0f; bool hasprev = false;

    auto impute = [&](int i, float xa, float xc, int wb) {
        bool nanp = (xa != xa) || (xc != xc);
        unsigned long long bal = __ballot(nanp);
        bool m = ((bal >> (16 * g)) & 0xFFFFull) != 0ull;
        float ia = m ? xp0 : xa;
        float ic = m ? xp1 : xc;
        xb[wb][ib][fx]      = (f16)ia;
        xb[wb][ib][fx + 16] = (f16)ic;
        if (!m) { xp0 = xa; xp1 = xc; }
        float tcur = tb[i];
        float tdel = (i == 0) ? 0.0f : (tcur - tb[i - 1]);
        float texp = hasprev ? (tcur - tprev) : tdel;
        if (fx == 0) {
            h2 mt = { (f16)(m ? 1.0f : 0.0f), (f16)texp };
            *(h2*)&xb[wb][ib][32] = mt;
        }
        if (!m) { hasprev = true; tprev = tcur; }
    };

    // ---- prologue: tb, zero panels, bias-1 col, impute(0) ----
    for (int idx = tid; idx < SS; idx += NT) tb[idx] = t_in[idx];
    {
        int* z0 = (int*)&h0b[0][0][0];
        for (int idx = tid; idx < 2 * BS * HSTR / 2; idx += NT) z0[idx] = 0;
        int* z1 = (int*)&h1b[0][0][0];
        for (int idx = tid; idx < 2 * BS * HSTR / 2; idx += NT) z1[idx] = 0;
        int* z2 = (int*)&xb[0][0][0];
        for (int idx = tid; idx < 2 * BS * XSTR / 2; idx += NT) z2[idx] = 0;
    }
    __syncthreads();
    if (tid < 32) xb[tid >> 4][tid & 15][34] = (f16)1.0f;   // bias-1 column
    {
        float xa0 = xptr[fx], xc0 = xptr[fx + 16];
        impute(0, xa0, xc0, 0);
    }
    __syncthreads();

    const f4 z4 = {0.f, 0.f, 0.f, 0.f};

    for (int i = 0; i <= SS; ++i) {
        const int pi = i & 1;
        const bool doL0 = (i < SS), doL1 = (i > 0), doImp = (i + 1 < SS);

        // early global prefetch for next imputation
        float xa_n = 0.0f, xc_n = 0.0f;
        if (doImp) {
            const float* xr = xptr + (size_t)(i + 1) * DD;
            xa_n = xr[fx]; xc_n = xr[fx + 16];
        }

        const f16* bx  = &xb [pi    ][cb][0];   // x(i) + bias col
        const f16* bh0 = &h0b[pi ^ 1][cb][0];   // h0(i-1)
        const f16* bh1 = &h1b[pi    ][cb][0];   // h1(i-2)

        // B-frags: x first, then h0, then h1 (each reused by both tiles)
        i4 BX0 = *(const i4*)(bx + 8 * g);
        i4 BX1 = *(const i4*)(bx + 32 + 8 * g);
        i4 BH0[4], BH1[4];
        #pragma unroll
        for (int ks = 0; ks < 4; ks++) BH0[ks] = *(const i4*)(bh0 + 32 * ks + 8 * g);

        f4 aR0[2], aZ0[2], aX0[2], aH0[2], aR1[2], aZ1[2], aX1[2], aH1[2];

        // x phase: gx0 (+ folded biases) -> L0 {r,z,ngx}   [A in arch]
        #pragma unroll
        for (int t = 0; t < 2; t++) {
            aR0[t] = mfma_v(axf[t][0][0], BX0, z4);
            aZ0[t] = mfma_v(axf[t][1][0], BX0, z4);
            aX0[t] = mfma_v(axf[t][2][0], BX0, z4);
            aR0[t] = mfma_v(axf[t][0][1], BX1, aR0[t]);
            aZ0[t] = mfma_v(axf[t][1][1], BX1, aZ0[t]);
            aX0[t] = mfma_v(axf[t][2][1], BX1, aX0[t]);
        }
        #pragma unroll
        for (int ks = 0; ks < 4; ks++) BH1[ks] = *(const i4*)(bh1 + 32 * ks + 8 * g);

        // h0 phase: gh0 -> L0 {r,z,ngh}; gx1 -> L1 {r,z,ngx}   [A in acc]
        #pragma unroll
        for (int t = 0; t < 2; t++) {
            aH0[t] = mfma_a(ah0f[t][2][0], BH0[0], z4);
            aR1[t] = mfma_a(ax1f[t][0][0], BH0[0], z4);
            aZ1[t] = mfma_a(ax1f[t][1][0], BH0[0], z4);
            aX1[t] = mfma_a(ax1f[t][2][0], BH0[0], z4);
            aR0[t] = mfma_a(ah0f[t][0][0], BH0[0], aR0[t]);
            aZ0[t] = mfma_a(ah0f[t][1][0], BH0[0], aZ0[t]);
            #pragma unroll
            for (int ks = 1; ks < 4; ks++) {
                aR0[t] = mfma_a(ah0f[t][0][ks], BH0[ks], aR0[t]);
                aZ0[t] = mfma_a(ah0f[t][1][ks], BH0[ks], aZ0[t]);
                aH0[t] = mfma_a(ah0f[t][2][ks], BH0[ks], aH0[t]);
                aR1[t] = mfma_a(ax1f[t][0][ks], BH0[ks], aR1[t]);
                aZ1[t] = mfma_a(ax1f[t][1][ks], BH0[ks], aZ1[t]);
                aX1[t] = mfma_a(ax1f[t][2][ks], BH0[ks], aX1[t]);
            }
        }
        // h1 phase: gh1 -> L1 {r,z,ngh}   [r via acc; z,n via arch]
        #pragma unroll
        for (int t = 0; t < 2; t++) {
            aH1[t] = mfma_v(ah1f[t][2][0], BH1[0], z4);
            aR1[t] = mfma_a(ah1f[t][0][0], BH1[0], aR1[t]);
            aZ1[t] = mfma_v(ah1f[t][1][0], BH1[0], aZ1[t]);
            #pragma unroll
            for (int ks = 1; ks < 4; ks++) {
                aR1[t] = mfma_a(ah1f[t][0][ks], BH1[ks], aR1[t]);
                aZ1[t] = mfma_v(ah1f[t][1][ks], BH1[ks], aZ1[t]);
                aH1[t] = mfma_v(ah1f[t][2][ks], BH1[ks], aH1[t]);
            }
        }

        // imputation for step i+1 (fills the MFMA drain shadow)
        if (doImp) impute(i + 1, xa_n, xc_n, pi ^ 1);

        // drain: MFMA write -> VALU read needs ~18 waits; accs threaded.
        ACC_GUARD(aR0[0], aZ0[0], aX0[0], aH0[0], aR1[0], aZ1[0], aX1[0], aH1[0]);
        ACC_GUARD(aR0[1], aZ0[1], aX0[1], aH0[1], aR1[1], aZ1[1], aX1[1], aH1[1]);

        // ---- lane-local gate updates (row j = 32w+16t+4g+e, batch cb) ----
        if (doL0) {
            #pragma unroll
            for (int t = 0; t < 2; t++) {
                #pragma unroll
                for (int e = 0; e < 4; e++) {
                    float rr = fast_sigm(aR0[t][e]);            // biases folded
                    float zz = fast_sigm(aZ0[t][e]);
                    float nn = fast_tanh(aX0[t][e]
                               + rr * (aH0[t][e] + (float)bnh0[t][e >> 1][e & 1]));
                    hr0[t][e] = nn + zz * (hr0[t][e] - nn);
                }
                union { h2 h[2]; int2 d; } up;
                up.h[0] = h2{(f16)hr0[t][0], (f16)hr0[t][1]};
                up.h[1] = h2{(f16)hr0[t][2], (f16)hr0[t][3]};
                *(int2*)&h0b[pi][cb][32 * w + 16 * t + 4 * g] = up.d;   // h0(i)
            }
        }
        if (doL1) {
            #pragma unroll
            for (int t = 0; t < 2; t++) {
                #pragma unroll
                for (int e = 0; e < 4; e++) {
                    float rr = fast_sigm(aR1[t][e] + (float)brz1[t][e][0]);
                    float zz = fast_sigm(aZ1[t][e] + (float)brz1[t][e][1]);
                    float nn = fast_tanh(aX1[t][e] + (float)bn1[t][e][0]
                               + rr * (aH1[t][e] + (float)bn1[t][e][1]));
                    hr1[t][e] = nn + zz * (hr1[t][e] - nn);
                }
                union { h2 h[2]; int2 d; } up;
                up.h[0] = h2{(f16)hr1[t][0], (f16)hr1[t][1]};
                up.h[1] = h2{(f16)hr1[t][2], (f16)hr1[t][3]};
                *(int2*)&h1b[pi ^ 1][cb][32 * w + 16 * t + 4 * g] = up.d; // h1(i-1)
            }
        }
        __syncthreads();   // h0(i), h1(i-1), x(i+1) visible for next step
    }

    // hr1 = h1(SS-1): final hidden of layer 1
    #pragma unroll
    for (int t = 0; t < 2; t++) {
        float* op = out + (size_t)(blk * BS + cb) * HH + 32 * w + 16 * t + 4 * g;
        *(float4*)op = make_float4(hr1[t][0], hr1[t][1], hr1[t][2], hr1[t][3]);
    }
}

extern "C" void kernel_launch(void* const* d_in, const int* in_sizes, int n_in,
                              void* d_out, int out_size, void* d_ws, size_t ws_size,
                              hipStream_t stream) {
    gru_fused<<<dim3(NBLK), dim3(NT), 0, stream>>>(
        (const float*)d_in[0], (const float*)d_in[1],
        (const float*)d_in[2], (const float*)d_in[3],
        (const float*)d_in[4], (const float*)d_in[5],
        (const float*)d_in[6], (const float*)d_in[7],
        (const float*)d_in[8], (const float*)d_in[9],
        (float*)d_out, (char*)d_ws);
}